// Round 17
// baseline (112.095 us; speedup 1.0000x reference)
//
#include <hip/hip_runtime.h>

#define N_NODES 384
#define CCH 256        // channels
#define HT 60          // height
#define CH (CCH*HT)    // 15360 elements per node slab
#define CH4 (CH/4)     // 3840 4-vectors
#define LN_EPS 1e-5f
#define CHK 96         // apply: per-chunk edge stats cached in LDS

typedef __attribute__((ext_vector_type(8))) short bf16x8;
typedef __attribute__((ext_vector_type(4))) float f32x4;

__device__ inline unsigned short f2bf(float f) {
    unsigned int u = __float_as_uint(f);
    unsigned int r = (u + 0x7FFF + ((u >> 16) & 1)) >> 16;   // RNE
    return (unsigned short)r;
}
__device__ inline float bf2f(unsigned short u) {
    return __uint_as_float(((unsigned int)u) << 16);
}

// Scal layout: [0..4] SM_j  [5] Sbias  [6..10] Mb_j  [11] Sb2  [12..36] G[j*5+k]
// ---- setup: blocks 0..127 Wfrag; block 128 M/bias0 + Scal (parallel) ----
__global__ __launch_bounds__(1024) void k_setup(const float* __restrict__ Wc,
                                                const float* __restrict__ We,
                                                const float* __restrict__ be,
                                                unsigned short* __restrict__ Wfrag,
                                                float* __restrict__ M,
                                                float* __restrict__ bias0,
                                                float* __restrict__ Scal) {
    __shared__ float Ml[5 * 256];
    __shared__ float bl[256];
    int tid = threadIdx.x;
    if (blockIdx.x < 128) {
        int idx = blockIdx.x * 1024 + tid;             // 131072 total
        int j = idx & 7, lane = (idx >> 3) & 63, ks = (idx >> 9) & 7, mt = idx >> 12;
        int o = mt * 16 + (lane & 15);
        int c = ks * 32 + (lane >> 4) * 8 + j;
        float v;
        if (o < 256) v = Wc[o * 768 + c] - Wc[o * 768 + 256 + c];   // W1 - W2
        else         v = Wc[(o - 256) * 768 + 256 + c];             // W2
        Wfrag[idx] = f2bf(v);
        return;
    }
    // ---- block 128: M/bias0 ----
    if (tid < 256) {
        int o = tid;
        float m0=0,m1=0,m2=0,m3=0,m4=0,bb=0;
        for (int k = 0; k < 256; ++k) {
            float w3 = Wc[o * 768 + 512 + k];
            m0 += We[0*256+k] * w3;
            m1 += We[1*256+k] * w3;
            m2 += We[2*256+k] * w3;
            m3 += We[3*256+k] * w3;
            m4 += We[4*256+k] * w3;
            bb += be[k] * w3;
        }
        M[0*256+o]=m0; M[1*256+o]=m1; M[2*256+o]=m2; M[3*256+o]=m3; M[4*256+o]=m4;
        bias0[o] = bb;
        Ml[0*256+o]=m0; Ml[1*256+o]=m1; Ml[2*256+o]=m2; Ml[3*256+o]=m3; Ml[4*256+o]=m4;
        bl[o] = bb;
    }
    __syncthreads();
    // ---- Scal: 37 reductions, wave-parallel (waves 0..3 of tid<256) ----
    if (tid < 256) {
        int w = tid >> 6, lane = tid & 63;
        for (int q = w; q < 37; q += 4) {
            float s = 0.f;
#pragma unroll
            for (int r = 0; r < 4; ++r) {
                int o = lane + 64 * r;
                float v;
                if (q < 5)       v = Ml[q * 256 + o];
                else if (q == 5) v = bl[o];
                else if (q < 11) v = Ml[(q - 6) * 256 + o] * bl[o];
                else if (q == 11) v = bl[o] * bl[o];
                else {
                    int t = q - 12, j = t / 5, k = t % 5;
                    v = Ml[j * 256 + o] * Ml[k * 256 + o];
                }
                s += v;
            }
#pragma unroll
            for (int o2 = 32; o2 >= 1; o2 >>= 1) s += __shfl_xor(s, o2, 64);
            if (lane == 0) Scal[q] = s;
        }
    }
}

// ---- per-node GEMM via MFMA, split by h-half (unchanged, proven) ----
__global__ __launch_bounds__(256) void k_node_mfma(const float* __restrict__ x,
                                                   const unsigned short* __restrict__ Wfrag,
                                                   unsigned short* __restrict__ Abf,
                                                   unsigned short* __restrict__ Bbf) {
    __shared__ unsigned short xT[32 * 256];   // 16 KiB, [h_local][c] bf16, swizzled
    int n = blockIdx.x, half = blockIdx.y, tid = threadIdx.x;

    const float4* xg = (const float4*)(x + (size_t)n * CH);
    if (half == 0) {
        for (int i = tid; i < 2048; i += 256) {
            int c = i >> 3, jj = i & 7;
            int r0 = jj * 4;
            float4 v = xg[c * 15 + jj];
            xT[(r0+0) * 256 + (c ^ (((r0+0) & 7) << 3))] = f2bf(v.x);
            xT[(r0+1) * 256 + (c ^ (((r0+1) & 7) << 3))] = f2bf(v.y);
            xT[(r0+2) * 256 + (c ^ (((r0+2) & 7) << 3))] = f2bf(v.z);
            xT[(r0+3) * 256 + (c ^ (((r0+3) & 7) << 3))] = f2bf(v.w);
        }
    } else {
        for (int i = tid; i < 4 * 256; i += 256) {
            int r = 28 + (i >> 8), c = i & 255;
            xT[r * 256 + (c ^ ((r & 7) << 3))] = 0;
        }
        for (int i = tid; i < 1792; i += 256) {
            int c = i / 7, jj = i - c * 7;
            int r0 = jj * 4;
            float4 v = xg[c * 15 + 8 + jj];
            xT[(r0+0) * 256 + (c ^ (((r0+0) & 7) << 3))] = f2bf(v.x);
            xT[(r0+1) * 256 + (c ^ (((r0+1) & 7) << 3))] = f2bf(v.y);
            xT[(r0+2) * 256 + (c ^ (((r0+2) & 7) << 3))] = f2bf(v.z);
            xT[(r0+3) * 256 + (c ^ (((r0+3) & 7) << 3))] = f2bf(v.w);
        }
    }
    __syncthreads();

    int w = tid >> 6, lane = tid & 63;
    int l15 = lane & 15, lg = lane >> 4;

    f32x4 acc[8][2];
#pragma unroll
    for (int mt = 0; mt < 8; ++mt)
#pragma unroll
        for (int nt = 0; nt < 2; ++nt)
            acc[mt][nt] = (f32x4){0.f, 0.f, 0.f, 0.f};

    const unsigned short* wbase = Wfrag + ((size_t)(w * 8) * 8) * 64 * 8;
    for (int ks = 0; ks < 8; ++ks) {
        bf16x8 bfr[2];
#pragma unroll
        for (int nt = 0; nt < 2; ++nt) {
            int row = nt * 16 + l15;
            int col = ks * 32 + lg * 8;
            int idx = row * 256 + (col ^ ((row & 7) << 3));
            bfr[nt] = *(const bf16x8*)(&xT[idx]);
        }
#pragma unroll
        for (int mt = 0; mt < 8; ++mt) {
            const bf16x8 afr = *(const bf16x8*)(wbase + (((size_t)mt * 8 + ks) * 64 + lane) * 8);
#pragma unroll
            for (int nt = 0; nt < 2; ++nt)
                acc[mt][nt] = __builtin_amdgcn_mfma_f32_16x16x32_bf16(afr, bfr[nt], acc[mt][nt], 0, 0, 0);
        }
    }

#pragma unroll
    for (int mt = 0; mt < 8; ++mt) {
        int mtg = w * 8 + mt;
        int obase = mtg * 16 + 4 * lg;
        unsigned short* dst0 = (obase < 256)
            ? (Abf + (size_t)n * CH + (size_t)obase * 60)
            : (Bbf + (size_t)n * CH + (size_t)(obase - 256) * 60);
#pragma unroll
        for (int nt = 0; nt < 2; ++nt) {
            int h = half * 32 + nt * 16 + l15;
            if (h < 60) {
#pragma unroll
                for (int r = 0; r < 4; ++r)
                    dst0[r * 60 + h] = f2bf(acc[mt][nt][r]);
            }
        }
    }
}

// ---- prep + edge-dots: b0 CSR; b1..384 node scalars + projections;
// b385.. wave per (edge,eighth): c-slice -> cbuf, dot -> EPd. All race-free.
__global__ __launch_bounds__(256) void k_prepdots(const unsigned short* __restrict__ Abf,
                                                  const unsigned short* __restrict__ Bbf,
                                                  const float* __restrict__ ea,
                                                  const float* __restrict__ M,
                                                  const float* __restrict__ bias0,
                                                  const int* __restrict__ srcA,
                                                  const int* __restrict__ dstA, int E,
                                                  float4* __restrict__ Sc,
                                                  float* __restrict__ NodeProj,
                                                  int* __restrict__ offs,
                                                  int* __restrict__ elist,
                                                  float* __restrict__ EPd,
                                                  float* __restrict__ cbuf) {
    int b = blockIdx.x;
    int tid = threadIdx.x, w = tid >> 6, lane = tid & 63;
    if (b == 0) {
        // ---- CSR build, 256 threads, LDS counters, deterministic ----
        __shared__ int cnt[N_NODES];
        __shared__ int sc0[N_NODES], sc1[N_NODES];
        for (int i = tid; i < N_NODES; i += 256) cnt[i] = 0;
        __syncthreads();
        for (int e = tid; e < E; e += 256) atomicAdd(&cnt[dstA[e]], 1);
        __syncthreads();
        for (int i = tid; i < N_NODES; i += 256) sc0[i] = cnt[i];
        __syncthreads();
        int flip = 0;
        for (int d = 1; d < N_NODES; d <<= 1) {      // 1..256
            const int* s_ = flip ? sc1 : sc0;
            int* d_ = flip ? sc0 : sc1;
            for (int i = tid; i < N_NODES; i += 256)
                d_[i] = s_[i] + (i >= d ? s_[i - d] : 0);
            __syncthreads();
            flip ^= 1;
        }
        const int* pos = flip ? sc1 : sc0;           // inclusive prefix
        for (int i = tid; i < N_NODES; i += 256) {
            offs[i + 1] = pos[i];
            cnt[i] = (i == 0) ? 0 : pos[i - 1];      // cursor = exclusive prefix
        }
        if (tid == 0) offs[0] = 0;
        __syncthreads();
        for (int e = tid; e < E; e += 256) {
            int d = dstA[e];
            elist[atomicAdd(&cnt[d], 1)] = e;
        }
        __syncthreads();
        for (int n2 = tid; n2 < N_NODES; n2 += 256) {
            int lo = (n2 == 0) ? 0 : pos[n2 - 1], hi = pos[n2];
            for (int i = lo + 1; i < hi; ++i) {
                int key = elist[i]; int j = i - 1;
                while (j >= lo && elist[j] > key) { elist[j + 1] = elist[j]; --j; }
                elist[j + 1] = key;
            }
        }
        return;
    }
    if (b < 1 + N_NODES) {
        // ---- per-node: row sums rA/rB (LDS), Sc totals, 12 projections ----
        __shared__ float red[16];
        __shared__ float rA[256], rB[256];
        int n = b - 1;
        const ushort4* Ab = (const ushort4*)(Abf + (size_t)n * CH + tid * 60);
        const ushort4* Bb = (const ushort4*)(Bbf + (size_t)n * CH + tid * 60);
        float rsA = 0.f, qA = 0.f, rsB = 0.f, qB = 0.f;
#pragma unroll
        for (int i = 0; i < 15; ++i) {
            ushort4 a = Ab[i], bb2 = Bb[i];
#pragma unroll
            for (int j = 0; j < 4; ++j) {
                float va = bf2f(((const unsigned short*)&a)[j]);
                float vb = bf2f(((const unsigned short*)&bb2)[j]);
                rsA += va; qA += va * va;
                rsB += vb; qB += vb * vb;
            }
        }
        rA[tid] = rsA; rB[tid] = rsB;
        float sA = rsA, sB = rsB;
#pragma unroll
        for (int o = 32; o >= 1; o >>= 1) {
            sA += __shfl_xor(sA, o, 64); qA += __shfl_xor(qA, o, 64);
            sB += __shfl_xor(sB, o, 64); qB += __shfl_xor(qB, o, 64);
        }
        if (lane == 0) { red[w*4]=sA; red[w*4+1]=qA; red[w*4+2]=sB; red[w*4+3]=qB; }
        __syncthreads();
        if (tid == 0) {
            Sc[n] = make_float4(red[0]+red[4]+red[8]+red[12],
                                red[1]+red[5]+red[9]+red[13],
                                red[2]+red[6]+red[10]+red[14],
                                red[3]+red[7]+red[11]+red[15]);
        }
        // projections: q 0..4 P_j=rA.M_j, 5 PA0=rA.b, 6..10 Q_j=rB.M_j, 11 QB0=rB.b
        for (int q = w; q < 12; q += 4) {
            float s = 0.f;
#pragma unroll
            for (int r = 0; r < 4; ++r) {
                int o = lane + 64 * r;
                float coef = (q == 5 || q == 11) ? bias0[o] : M[((q < 5) ? q : q - 6) * 256 + o];
                float rv = (q < 6) ? rA[o] : rB[o];
                s += rv * coef;
            }
#pragma unroll
            for (int o2 = 32; o2 >= 1; o2 >>= 1) s += __shfl_xor(s, o2, 64);
            if (lane == 0) NodeProj[(size_t)n * 12 + q] = s;
        }
        return;
    }
    // ---- edge dots: wave per (edge, eighth); stride-8 cg8 -> L2 affinity ----
    {
        int g = b - (1 + N_NODES);
        int cg8 = g & 7;
        int ew = g >> 3;
        int e = ew * 4 + w;
        if (e >= E) return;
        int s = srcA[e], d = dstA[e];

        // c-coefficient for this eighth's 32 channels (lanes 0..31)
        if (lane < 32) {
            int o = cg8 * 32 + lane;
            float ev0 = ea[e*5], ev1 = ea[e*5+1], ev2 = ea[e*5+2],
                  ev3 = ea[e*5+3], ev4 = ea[e*5+4];
            float c = bias0[o] + ev0*M[o] + ev1*M[256+o] + ev2*M[512+o]
                    + ev3*M[768+o] + ev4*M[1024+o];
            cbuf[(size_t)e * 256 + o] = c;
        }

        // cross-dot over this eighth (480 ushort4 = 7*64 + 32)
        const ushort4* Ab = (const ushort4*)(Abf + (size_t)d * CH + (size_t)cg8 * 1920);
        const ushort4* Bb = (const ushort4*)(Bbf + (size_t)s * CH + (size_t)cg8 * 1920);
        float dot = 0.f;
#pragma unroll
        for (int r = 0; r < 7; ++r) {
            int i = lane + 64 * r;
            ushort4 a = Ab[i], bb2 = Bb[i];
            dot += bf2f(a.x) * bf2f(bb2.x) + bf2f(a.y) * bf2f(bb2.y)
                 + bf2f(a.z) * bf2f(bb2.z) + bf2f(a.w) * bf2f(bb2.w);
        }
        if (lane < 32) {
            int i = lane + 448;
            ushort4 a = Ab[i], bb2 = Bb[i];
            dot += bf2f(a.x) * bf2f(bb2.x) + bf2f(a.y) * bf2f(bb2.y)
                 + bf2f(a.z) * bf2f(bb2.z) + bf2f(a.w) * bf2f(bb2.w);
        }
#pragma unroll
        for (int o2 = 32; o2 >= 1; o2 >>= 1)
            dot += __shfl_xor(dot, o2, 64);
        if (lane == 0) EPd[(size_t)e * 8 + cg8] = dot;
    }
}

// ---- apply: 8-way channel split, XCD affinity; per-edge stats assembled in a
// light pre-loop (scalar identities + EP dot gather), cached in LDS.
__global__ __launch_bounds__(256) void k_apply(const unsigned short* __restrict__ Abf,
                                               const unsigned short* __restrict__ Bbf,
                                               const float* __restrict__ cbuf,
                                               const float* __restrict__ EPd,
                                               const float4* __restrict__ Sc,
                                               const float* __restrict__ NodeProj,
                                               const float* __restrict__ Scal,
                                               const float* __restrict__ ea,
                                               const int* __restrict__ srcArr,
                                               const int* __restrict__ offsets,
                                               const int* __restrict__ elist,
                                               const float* __restrict__ gamma,
                                               const float* __restrict__ beta,
                                               float* __restrict__ out) {
    __shared__ float2 stl[CHK];
    int b = blockIdx.x;
    int cg8 = b & 7;
    int n = b >> 3;
    int tid = threadIdx.x, w = tid >> 6, lane = tid & 63;
    size_t sbase = (size_t)n * CH + (size_t)cg8 * 1920;
    const ushort4* Ab = (const ushort4*)(Abf + sbase);
    const float4*  g4 = (const float4*)(gamma + (size_t)cg8 * 1920);
    const float4*  b4 = (const float4*)(beta  + (size_t)cg8 * 1920);
    bool act1 = (tid < 224);                   // 480 = 256 + 224 vec4s

    float4 scd = Sc[n];
    float PA0n = NodeProj[(size_t)n * 12 + 5];
    float Pn0 = NodeProj[(size_t)n * 12 + 0], Pn1 = NodeProj[(size_t)n * 12 + 1],
          Pn2 = NodeProj[(size_t)n * 12 + 2], Pn3 = NodeProj[(size_t)n * 12 + 3],
          Pn4 = NodeProj[(size_t)n * 12 + 4];

    float4 af[2], gv[2], bv[2], acc[2];
    int ci[2];
#pragma unroll
    for (int r = 0; r < 2; ++r) {
        acc[r] = make_float4(0.f, 0.f, 0.f, 0.f);
        af[r] = make_float4(0.f, 0.f, 0.f, 0.f);
        gv[r] = make_float4(0.f, 0.f, 0.f, 0.f);
        bv[r] = make_float4(0.f, 0.f, 0.f, 0.f);
        ci[r] = 0;
    }
#pragma unroll
    for (int r = 0; r < 2; ++r) {
        if (r == 0 || act1) {
            int i = tid + 256 * r;
            ci[r] = i / 15;                    // channel within eighth (0..31)
            ushort4 aw = Ab[i];
            af[r].x = bf2f(aw.x); af[r].y = bf2f(aw.y);
            af[r].z = bf2f(aw.z); af[r].w = bf2f(aw.w);
            gv[r] = g4[i];
            bv[r] = b4[i];
        }
    }

    int lo = offsets[n], hi = offsets[n + 1];
    for (int base = lo; base < hi; base += CHK) {
        int cnt = min(CHK, hi - base);
        if (base != lo) __syncthreads();
        // ---- stats pre-loop: wave w handles edges base+w, base+w+4, ... ----
        for (int kk = w; kk < cnt; kk += 4) {
            int e = elist[base + kk];
            int s = srcArr[e];
            float dot = 0.f;
            if (lane < 8) dot = EPd[(size_t)e * 8 + lane];
            dot += __shfl_xor(dot, 4, 64);
            dot += __shfl_xor(dot, 2, 64);
            dot += __shfl_xor(dot, 1, 64);
            if (lane == 0) {
                float e0 = ea[e*5], e1 = ea[e*5+1], e2 = ea[e*5+2],
                      e3 = ea[e*5+3], e4 = ea[e*5+4];
                float sumc = Scal[5] + e0*Scal[0] + e1*Scal[1] + e2*Scal[2]
                           + e3*Scal[3] + e4*Scal[4];
                float sumc2 = Scal[11]
                    + 2.f * (e0*Scal[6] + e1*Scal[7] + e2*Scal[8] + e3*Scal[9] + e4*Scal[10]);
                float ev[5] = {e0, e1, e2, e3, e4};
#pragma unroll
                for (int j = 0; j < 5; ++j)
#pragma unroll
                    for (int k2 = 0; k2 < 5; ++k2)
                        sumc2 += ev[j] * ev[k2] * Scal[12 + j * 5 + k2];
                const float* nps = NodeProj + (size_t)s * 12;
                float dots = PA0n + e0*Pn0 + e1*Pn1 + e2*Pn2 + e3*Pn3 + e4*Pn4
                           + nps[11] + e0*nps[6] + e1*nps[7] + e2*nps[8]
                           + e3*nps[9] + e4*nps[10];
                float4 scs = Sc[s];
                float S1 = scd.x + scs.z + 60.f * sumc;
                float S2 = scd.y + scs.w + 60.f * sumc2 + 2.f * (dot + dots);
                float mu = S1 * (1.0f / (float)CH);
                float var = S2 * (1.0f / (float)CH) - mu * mu;
                stl[kk] = make_float2(mu, rsqrtf(var + LN_EPS));
            }
        }
        __syncthreads();
        // ---- apply loop over this chunk, edge-pair unrolled (R15 body) ----
        int k = 0;
        for (; k + 1 < cnt; k += 2) {
            int e0 = elist[base + k], e1 = elist[base + k + 1];
            int s0 = srcArr[e0], s1 = srcArr[e1];
            float2 st0 = stl[k], st1 = stl[k + 1];
            const ushort4* B0 = (const ushort4*)(Bbf + (size_t)s0 * CH + (size_t)cg8 * 1920);
            const ushort4* B1 = (const ushort4*)(Bbf + (size_t)s1 * CH + (size_t)cg8 * 1920);
            const float* c0 = cbuf + (size_t)e0 * 256 + cg8 * 32;
            const float* c1 = cbuf + (size_t)e1 * 256 + cg8 * 32;
#pragma unroll
            for (int r = 0; r < 2; ++r) {
                if (r == 0 || act1) {
                    int i = tid + 256 * r;
                    ushort4 bw0 = B0[i];
                    ushort4 bw1 = B1[i];
                    float cc0 = c0[ci[r]];
                    float cc1 = c1[ci[r]];
                    float m0x = af[r].x + bf2f(bw0.x) + cc0;
                    float m0y = af[r].y + bf2f(bw0.y) + cc0;
                    float m0z = af[r].z + bf2f(bw0.z) + cc0;
                    float m0w = af[r].w + bf2f(bw0.w) + cc0;
                    float m1x = af[r].x + bf2f(bw1.x) + cc1;
                    float m1y = af[r].y + bf2f(bw1.y) + cc1;
                    float m1z = af[r].z + bf2f(bw1.z) + cc1;
                    float m1w = af[r].w + bf2f(bw1.w) + cc1;
                    acc[r].x += fmaxf((m0x - st0.x) * st0.y * gv[r].x + bv[r].x, 0.f);
                    acc[r].y += fmaxf((m0y - st0.x) * st0.y * gv[r].y + bv[r].y, 0.f);
                    acc[r].z += fmaxf((m0z - st0.x) * st0.y * gv[r].z + bv[r].z, 0.f);
                    acc[r].w += fmaxf((m0w - st0.x) * st0.y * gv[r].w + bv[r].w, 0.f);
                    acc[r].x += fmaxf((m1x - st1.x) * st1.y * gv[r].x + bv[r].x, 0.f);
                    acc[r].y += fmaxf((m1y - st1.x) * st1.y * gv[r].y + bv[r].y, 0.f);
                    acc[r].z += fmaxf((m1z - st1.x) * st1.y * gv[r].z + bv[r].z, 0.f);
                    acc[r].w += fmaxf((m1w - st1.x) * st1.y * gv[r].w + bv[r].w, 0.f);
                }
            }
        }
        if (k < cnt) {
            int e = elist[base + k];
            int s = srcArr[e];
            float2 st = stl[k];
            const ushort4* Bb = (const ushort4*)(Bbf + (size_t)s * CH + (size_t)cg8 * 1920);
            const float* cc = cbuf + (size_t)e * 256 + cg8 * 32;
#pragma unroll
            for (int r = 0; r < 2; ++r) {
                if (r == 0 || act1) {
                    int i = tid + 256 * r;
                    float ccv = cc[ci[r]];
                    ushort4 bw = Bb[i];
                    float mx = af[r].x + bf2f(bw.x) + ccv;
                    float my = af[r].y + bf2f(bw.y) + ccv;
                    float mz = af[r].z + bf2f(bw.z) + ccv;
                    float mw = af[r].w + bf2f(bw.w) + ccv;
                    acc[r].x += fmaxf((mx - st.x) * st.y * gv[r].x + bv[r].x, 0.f);
                    acc[r].y += fmaxf((my - st.x) * st.y * gv[r].y + bv[r].y, 0.f);
                    acc[r].z += fmaxf((mz - st.x) * st.y * gv[r].z + bv[r].z, 0.f);
                    acc[r].w += fmaxf((mw - st.x) * st.y * gv[r].w + bv[r].w, 0.f);
                }
            }
        }
    }
    float4* ob = (float4*)(out + sbase);
#pragma unroll
    for (int r = 0; r < 2; ++r)
        if (r == 0 || act1) ob[tid + 256 * r] = acc[r];
}

extern "C" void kernel_launch(void* const* d_in, const int* in_sizes, int n_in,
                              void* d_out, int out_size, void* d_ws, size_t ws_size,
                              hipStream_t stream) {
    const float* x     = (const float*)d_in[0];
    const float* ea    = (const float*)d_in[1];
    const int*   ei    = (const int*)d_in[2];
    const float* We    = (const float*)d_in[3];
    const float* be    = (const float*)d_in[4];
    const float* Wc    = (const float*)d_in[5];
    const float* gamma = (const float*)d_in[6];
    const float* beta  = (const float*)d_in[7];
    const int E = in_sizes[2] / 2;
    const int* src = ei;
    const int* dst = ei + E;

    char* ws = (char*)d_ws;
    size_t off = 0;
    auto alloc = [&](size_t bytes) -> void* {
        void* p = ws + off;
        off += (bytes + 255) & ~(size_t)255;
        return p;
    };
    unsigned short* Abf    = (unsigned short*)alloc((size_t)N_NODES * CH * 2);
    unsigned short* Bbf    = (unsigned short*)alloc((size_t)N_NODES * CH * 2);
    float*          cbuf   = (float*)alloc((size_t)E * 256 * 4);
    unsigned short* Wfrag  = (unsigned short*)alloc(512 * 256 * 2);
    float*          M      = (float*)alloc(5 * 256 * 4);
    float*          bias0  = (float*)alloc(256 * 4);
    float*          Scal   = (float*)alloc(64 * 4);
    float4*         Sc     = (float4*)alloc((size_t)N_NODES * 16);
    float*          NodeProj = (float*)alloc((size_t)N_NODES * 12 * 4);
    float*          EPd    = (float*)alloc((size_t)E * 8 * 4);
    int*            offs   = (int*)alloc((N_NODES + 1) * 4);
    int*            elist  = (int*)alloc((size_t)E * 4);

    int ndot = ((E + 3) / 4) * 8;
    k_setup<<<129, 1024, 0, stream>>>(Wc, We, be, Wfrag, M, bias0, Scal);
    k_node_mfma<<<dim3(N_NODES, 2), 256, 0, stream>>>(x, Wfrag, Abf, Bbf);
    k_prepdots<<<1 + N_NODES + ndot, 256, 0, stream>>>(Abf, Bbf, ea, M, bias0, src, dst, E,
                                                       Sc, NodeProj, offs, elist, EPd, cbuf);
    k_apply<<<N_NODES * 8, 256, 0, stream>>>(Abf, Bbf, cbuf, EPd, Sc, NodeProj, Scal, ea,
                                             src, offs, elist, gamma, beta, (float*)d_out);
}

// Round 18
// 85.325 us; speedup vs baseline: 1.3137x; 1.3137x over previous
//
#include <hip/hip_runtime.h>

#define N_NODES 384
#define CCH 256        // channels
#define HT 60          // height
#define CH (CCH*HT)    // 15360 elements per node slab
#define CH4 (CH/4)     // 3840 4-vectors
#define LN_EPS 1e-5f

typedef __attribute__((ext_vector_type(8))) short bf16x8;
typedef __attribute__((ext_vector_type(4))) float f32x4;

__device__ inline unsigned short f2bf(float f) {
    unsigned int u = __float_as_uint(f);
    unsigned int r = (u + 0x7FFF + ((u >> 16) & 1)) >> 16;   // RNE
    return (unsigned short)r;
}
__device__ inline float bf2f(unsigned short u) {
    return __uint_as_float(((unsigned int)u) << 16);
}

// ---- setup: Wfrag conversion only (critical path for k_node_mfma).
// Logical A matrix: 512x256, rows 0..255 = W1-W2, rows 256..511 = W2.
__global__ __launch_bounds__(1024) void k_setup(const float* __restrict__ Wc,
                                                unsigned short* __restrict__ Wfrag) {
    int idx = blockIdx.x * 1024 + threadIdx.x;     // 131072 total
    int j = idx & 7, lane = (idx >> 3) & 63, ks = (idx >> 9) & 7, mt = idx >> 12;
    int o = mt * 16 + (lane & 15);
    int c = ks * 32 + (lane >> 4) * 8 + j;
    float v;
    if (o < 256) v = Wc[o * 768 + c] - Wc[o * 768 + 256 + c];   // W1 - W2
    else         v = Wc[(o - 256) * 768 + 256 + c];             // W2
    Wfrag[idx] = f2bf(v);
}

// ---- per-node GEMM via MFMA, split by h-half: block (n, half) computes
// [A;B](512 x 32h) = Wstacked(512x256) @ x[n](256 x 32h). x read ONCE total.
__global__ __launch_bounds__(256) void k_node_mfma(const float* __restrict__ x,
                                                   const unsigned short* __restrict__ Wfrag,
                                                   unsigned short* __restrict__ Abf,
                                                   unsigned short* __restrict__ Bbf) {
    __shared__ unsigned short xT[32 * 256];   // 16 KiB, [h_local][c] bf16, swizzled
    int n = blockIdx.x, half = blockIdx.y, tid = threadIdx.x;

    const float4* xg = (const float4*)(x + (size_t)n * CH);
    if (half == 0) {
        for (int i = tid; i < 2048; i += 256) {
            int c = i >> 3, jj = i & 7;
            int r0 = jj * 4;
            float4 v = xg[c * 15 + jj];
            xT[(r0+0) * 256 + (c ^ (((r0+0) & 7) << 3))] = f2bf(v.x);
            xT[(r0+1) * 256 + (c ^ (((r0+1) & 7) << 3))] = f2bf(v.y);
            xT[(r0+2) * 256 + (c ^ (((r0+2) & 7) << 3))] = f2bf(v.z);
            xT[(r0+3) * 256 + (c ^ (((r0+3) & 7) << 3))] = f2bf(v.w);
        }
    } else {
        for (int i = tid; i < 4 * 256; i += 256) {
            int r = 28 + (i >> 8), c = i & 255;
            xT[r * 256 + (c ^ ((r & 7) << 3))] = 0;
        }
        for (int i = tid; i < 1792; i += 256) {
            int c = i / 7, jj = i - c * 7;
            int r0 = jj * 4;
            float4 v = xg[c * 15 + 8 + jj];
            xT[(r0+0) * 256 + (c ^ (((r0+0) & 7) << 3))] = f2bf(v.x);
            xT[(r0+1) * 256 + (c ^ (((r0+1) & 7) << 3))] = f2bf(v.y);
            xT[(r0+2) * 256 + (c ^ (((r0+2) & 7) << 3))] = f2bf(v.z);
            xT[(r0+3) * 256 + (c ^ (((r0+3) & 7) << 3))] = f2bf(v.w);
        }
    }
    __syncthreads();

    int w = tid >> 6, lane = tid & 63;
    int l15 = lane & 15, lg = lane >> 4;

    f32x4 acc[8][2];
#pragma unroll
    for (int mt = 0; mt < 8; ++mt)
#pragma unroll
        for (int nt = 0; nt < 2; ++nt)
            acc[mt][nt] = (f32x4){0.f, 0.f, 0.f, 0.f};

    const unsigned short* wbase = Wfrag + ((size_t)(w * 8) * 8) * 64 * 8;
    for (int ks = 0; ks < 8; ++ks) {
        bf16x8 bfr[2];
#pragma unroll
        for (int nt = 0; nt < 2; ++nt) {
            int row = nt * 16 + l15;
            int col = ks * 32 + lg * 8;
            int idx = row * 256 + (col ^ ((row & 7) << 3));
            bfr[nt] = *(const bf16x8*)(&xT[idx]);
        }
#pragma unroll
        for (int mt = 0; mt < 8; ++mt) {
            const bf16x8 afr = *(const bf16x8*)(wbase + (((size_t)mt * 8 + ks) * 64 + lane) * 8);
#pragma unroll
            for (int nt = 0; nt < 2; ++nt)
                acc[mt][nt] = __builtin_amdgcn_mfma_f32_16x16x32_bf16(afr, bfr[nt], acc[mt][nt], 0, 0, 0);
        }
    }

#pragma unroll
    for (int mt = 0; mt < 8; ++mt) {
        int mtg = w * 8 + mt;
        int obase = mtg * 16 + 4 * lg;
        unsigned short* dst0 = (obase < 256)
            ? (Abf + (size_t)n * CH + (size_t)obase * 60)
            : (Bbf + (size_t)n * CH + (size_t)(obase - 256) * 60);
#pragma unroll
        for (int nt = 0; nt < 2; ++nt) {
            int h = half * 32 + nt * 16 + l15;
            if (h < 60) {
#pragma unroll
                for (int r = 0; r < 4; ++r)
                    dst0[r * 60 + h] = f2bf(acc[mt][nt][r]);
            }
        }
    }
}

// ---- prep + dots: b0 CSR; b1 M/bias0; b2..385 per-node scalars;
// b386.. per-(edge,eighth) cross-dots (wave per edge, cg8 -> L2-resident eighths)
__global__ __launch_bounds__(256) void k_prepdots(const unsigned short* __restrict__ Abf,
                                                  const unsigned short* __restrict__ Bbf,
                                                  const float* __restrict__ Wc,
                                                  const float* __restrict__ We,
                                                  const float* __restrict__ be,
                                                  const int* __restrict__ srcA,
                                                  const int* __restrict__ dstA, int E,
                                                  float* __restrict__ RAB,
                                                  float4* __restrict__ Sc,
                                                  float* __restrict__ M,
                                                  float* __restrict__ bias0,
                                                  int* __restrict__ offs,
                                                  int* __restrict__ elist,
                                                  float* __restrict__ Gp8) {
    int b = blockIdx.x;
    int tid = threadIdx.x, w = tid >> 6, lane = tid & 63;
    if (b == 0) {
        // ---- CSR build, 256 threads, LDS counters, deterministic ----
        __shared__ int cnt[N_NODES];
        __shared__ int sc0[N_NODES], sc1[N_NODES];
        for (int i = tid; i < N_NODES; i += 256) cnt[i] = 0;
        __syncthreads();
        for (int e = tid; e < E; e += 256) atomicAdd(&cnt[dstA[e]], 1);
        __syncthreads();
        for (int i = tid; i < N_NODES; i += 256) sc0[i] = cnt[i];
        __syncthreads();
        int flip = 0;
        for (int d = 1; d < N_NODES; d <<= 1) {      // 1..256
            const int* s_ = flip ? sc1 : sc0;
            int* d_ = flip ? sc0 : sc1;
            for (int i = tid; i < N_NODES; i += 256)
                d_[i] = s_[i] + (i >= d ? s_[i - d] : 0);
            __syncthreads();
            flip ^= 1;
        }
        const int* pos = flip ? sc1 : sc0;           // inclusive prefix
        for (int i = tid; i < N_NODES; i += 256) {
            offs[i + 1] = pos[i];
            cnt[i] = (i == 0) ? 0 : pos[i - 1];      // cursor = exclusive prefix
        }
        if (tid == 0) offs[0] = 0;
        __syncthreads();
        for (int e = tid; e < E; e += 256) {
            int d = dstA[e];
            elist[atomicAdd(&cnt[d], 1)] = e;
        }
        __syncthreads();
        for (int n2 = tid; n2 < N_NODES; n2 += 256) {
            int lo = (n2 == 0) ? 0 : pos[n2 - 1], hi = pos[n2];
            for (int i = lo + 1; i < hi; ++i) {
                int key = elist[i]; int j = i - 1;
                while (j >= lo && elist[j] > key) { elist[j + 1] = elist[j]; --j; }
                elist[j + 1] = key;
            }
        }
        return;
    }
    if (b == 1) {
        // ---- M/bias0 ----
        int o = tid;
        float m0=0,m1=0,m2=0,m3=0,m4=0,bb=0;
        for (int k = 0; k < 256; ++k) {
            float w3 = Wc[o * 768 + 512 + k];
            m0 += We[0*256+k] * w3;
            m1 += We[1*256+k] * w3;
            m2 += We[2*256+k] * w3;
            m3 += We[3*256+k] * w3;
            m4 += We[4*256+k] * w3;
            bb += be[k] * w3;
        }
        M[0*256+o]=m0; M[1*256+o]=m1; M[2*256+o]=m2; M[3*256+o]=m3; M[4*256+o]=m4;
        bias0[o] = bb;
        return;
    }
    if (b < 2 + N_NODES) {
        // ---- per-node scalars: RA/RB row sums, SA/QA/SB/QB totals ----
        __shared__ float red[16];
        int n = b - 2;
        const ushort4* Ab = (const ushort4*)(Abf + (size_t)n * CH + tid * 60);
        const ushort4* Bb = (const ushort4*)(Bbf + (size_t)n * CH + tid * 60);
        float rsA = 0.f, qA = 0.f, rsB = 0.f, qB = 0.f;
#pragma unroll
        for (int i = 0; i < 15; ++i) {
            ushort4 a = Ab[i], bb2 = Bb[i];
#pragma unroll
            for (int j = 0; j < 4; ++j) {
                float va = bf2f(((const unsigned short*)&a)[j]);
                float vb = bf2f(((const unsigned short*)&bb2)[j]);
                rsA += va; qA += va * va;
                rsB += vb; qB += vb * vb;
            }
        }
        RAB[(size_t)n * 512 + tid] = rsA;
        RAB[(size_t)n * 512 + 256 + tid] = rsB;
        float sA = rsA, sB = rsB;
#pragma unroll
        for (int o = 32; o >= 1; o >>= 1) {
            sA += __shfl_xor(sA, o, 64); qA += __shfl_xor(qA, o, 64);
            sB += __shfl_xor(sB, o, 64); qB += __shfl_xor(qB, o, 64);
        }
        if (lane == 0) { red[w*4]=sA; red[w*4+1]=qA; red[w*4+2]=sB; red[w*4+3]=qB; }
        __syncthreads();
        if (tid == 0) {
            Sc[n] = make_float4(red[0]+red[4]+red[8]+red[12],
                                red[1]+red[5]+red[9]+red[13],
                                red[2]+red[6]+red[10]+red[14],
                                red[3]+red[7]+red[11]+red[15]);
        }
        return;
    }
    // ---- cross-dots: wave per (edge, eighth). cg8 = g&7 keeps stride-8 blocks
    // on one XCD -> that XCD's A/B eighths (2x1.48 MB) stay L2-resident.
    {
        int g = b - (2 + N_NODES);
        int cg8 = g & 7;
        int ew = g >> 3;
        int e = ew * 4 + w;
        if (e >= E) return;
        int s = srcA[e], d = dstA[e];
        const ushort4* Ab = (const ushort4*)(Abf + (size_t)d * CH + (size_t)cg8 * 1920);
        const ushort4* Bb = (const ushort4*)(Bbf + (size_t)s * CH + (size_t)cg8 * 1920);
        float dot = 0.f;
#pragma unroll
        for (int r = 0; r < 7; ++r) {            // 480 = 7*64 + 32 ushort4
            int i = lane + 64 * r;
            ushort4 a = Ab[i], bb2 = Bb[i];
            dot += bf2f(a.x) * bf2f(bb2.x) + bf2f(a.y) * bf2f(bb2.y)
                 + bf2f(a.z) * bf2f(bb2.z) + bf2f(a.w) * bf2f(bb2.w);
        }
        if (lane < 32) {
            int i = lane + 448;
            ushort4 a = Ab[i], bb2 = Bb[i];
            dot += bf2f(a.x) * bf2f(bb2.x) + bf2f(a.y) * bf2f(bb2.y)
                 + bf2f(a.z) * bf2f(bb2.z) + bf2f(a.w) * bf2f(bb2.w);
        }
#pragma unroll
        for (int o2 = 32; o2 >= 1; o2 >>= 1)
            dot += __shfl_xor(dot, o2, 64);
        if (lane == 0) Gp8[(size_t)e * 8 + cg8] = dot;
    }
}

// ---- per-edge stats (edge-coefficient + LN stats assembly; Gp8 gather) ----
__global__ __launch_bounds__(256) void k_stats2(const float* __restrict__ ea,
                                                const float* __restrict__ M,
                                                const float* __restrict__ bias0,
                                                const int* __restrict__ srcA,
                                                const int* __restrict__ dstA, int E,
                                                const float* __restrict__ RAB,
                                                const float4* __restrict__ Sc,
                                                const float* __restrict__ Gp8,
                                                float* __restrict__ cbuf,
                                                float2* __restrict__ stats) {
    int w = threadIdx.x >> 6, lane = threadIdx.x & 63;
    int e = blockIdx.x * 4 + w;
    if (e >= E) return;
    int s = srcA[e], d = dstA[e];
    float ev0 = ea[e*5], ev1 = ea[e*5+1], ev2 = ea[e*5+2], ev3 = ea[e*5+3], ev4 = ea[e*5+4];
    float sc = 0.f, sc2 = 0.f, dots = 0.f;
#pragma unroll
    for (int r = 0; r < 4; ++r) {
        int o = lane + 64 * r;
        float c = bias0[o] + ev0*M[o] + ev1*M[256+o] + ev2*M[512+o] + ev3*M[768+o] + ev4*M[1024+o];
        cbuf[(size_t)e * 256 + o] = c;
        sc += c; sc2 += c * c;
        dots += (RAB[(size_t)d * 512 + o] + RAB[(size_t)s * 512 + 256 + o]) * c;
    }
    float g = (lane < 8) ? Gp8[(size_t)e * 8 + lane] : 0.f;
#pragma unroll
    for (int o2 = 32; o2 >= 1; o2 >>= 1) {
        sc   += __shfl_xor(sc, o2, 64);
        sc2  += __shfl_xor(sc2, o2, 64);
        dots += __shfl_xor(dots, o2, 64);
        g    += __shfl_xor(g, o2, 64);
    }
    if (lane == 0) {
        float4 scd = Sc[d], scs = Sc[s];
        float S1 = scd.x + scs.z + 60.f * sc;
        float S2 = scd.y + scs.w + 60.f * sc2 + 2.f * (g + dots);
        float mu = S1 * (1.0f / (float)CH);
        float var = S2 * (1.0f / (float)CH) - mu * mu;
        stats[e] = make_float2(mu, rsqrtf(var + LN_EPS));
    }
}

// ---- apply + aggregate: 8-way channel split, XCD affinity, edge unroll x4 ----
__global__ __launch_bounds__(256) void k_apply(const unsigned short* __restrict__ Abf,
                                               const unsigned short* __restrict__ Bbf,
                                               const float* __restrict__ cbuf,
                                               const float2* __restrict__ stats,
                                               const int* __restrict__ srcArr,
                                               const int* __restrict__ offsets,
                                               const int* __restrict__ elist,
                                               const float* __restrict__ gamma,
                                               const float* __restrict__ beta,
                                               float* __restrict__ out) {
    int b = blockIdx.x;
    int cg8 = b & 7;
    int n = b >> 3;
    int tid = threadIdx.x;
    size_t sbase = (size_t)n * CH + (size_t)cg8 * 1920;
    const ushort4* Ab = (const ushort4*)(Abf + sbase);
    const float4*  g4 = (const float4*)(gamma + (size_t)cg8 * 1920);
    const float4*  b4 = (const float4*)(beta  + (size_t)cg8 * 1920);
    bool act1 = (tid < 224);                   // 480 = 256 + 224 vec4s

    float4 af[2], gv[2], bv[2], acc[2];
    int ci[2];
#pragma unroll
    for (int r = 0; r < 2; ++r) {
        acc[r] = make_float4(0.f, 0.f, 0.f, 0.f);
        af[r] = make_float4(0.f, 0.f, 0.f, 0.f);
        gv[r] = make_float4(0.f, 0.f, 0.f, 0.f);
        bv[r] = make_float4(0.f, 0.f, 0.f, 0.f);
        ci[r] = 0;
    }
#pragma unroll
    for (int r = 0; r < 2; ++r) {
        if (r == 0 || act1) {
            int i = tid + 256 * r;
            ci[r] = i / 15;                    // channel within eighth (0..31)
            ushort4 aw = Ab[i];
            af[r].x = bf2f(aw.x); af[r].y = bf2f(aw.y);
            af[r].z = bf2f(aw.z); af[r].w = bf2f(aw.w);
            gv[r] = g4[i];
            bv[r] = b4[i];
        }
    }

    int lo = offsets[n], hi = offsets[n + 1];
    int k = lo;
    for (; k + 3 < hi; k += 4) {
        int e0 = elist[k], e1 = elist[k + 1], e2 = elist[k + 2], e3 = elist[k + 3];
        int s0 = srcArr[e0], s1 = srcArr[e1], s2 = srcArr[e2], s3 = srcArr[e3];
        float2 st0 = stats[e0], st1 = stats[e1], st2 = stats[e2], st3 = stats[e3];
        const ushort4* B0 = (const ushort4*)(Bbf + (size_t)s0 * CH + (size_t)cg8 * 1920);
        const ushort4* B1 = (const ushort4*)(Bbf + (size_t)s1 * CH + (size_t)cg8 * 1920);
        const ushort4* B2 = (const ushort4*)(Bbf + (size_t)s2 * CH + (size_t)cg8 * 1920);
        const ushort4* B3 = (const ushort4*)(Bbf + (size_t)s3 * CH + (size_t)cg8 * 1920);
        const float* c0 = cbuf + (size_t)e0 * 256 + cg8 * 32;
        const float* c1 = cbuf + (size_t)e1 * 256 + cg8 * 32;
        const float* c2 = cbuf + (size_t)e2 * 256 + cg8 * 32;
        const float* c3 = cbuf + (size_t)e3 * 256 + cg8 * 32;
#pragma unroll
        for (int r = 0; r < 2; ++r) {
            if (r == 0 || act1) {
                int i = tid + 256 * r;
                ushort4 bw0 = B0[i];
                ushort4 bw1 = B1[i];
                ushort4 bw2 = B2[i];
                ushort4 bw3 = B3[i];
                float cc0 = c0[ci[r]];
                float cc1 = c1[ci[r]];
                float cc2 = c2[ci[r]];
                float cc3 = c3[ci[r]];
                acc[r].x += fmaxf((af[r].x + bf2f(bw0.x) + cc0 - st0.x) * st0.y * gv[r].x + bv[r].x, 0.f);
                acc[r].y += fmaxf((af[r].y + bf2f(bw0.y) + cc0 - st0.x) * st0.y * gv[r].y + bv[r].y, 0.f);
                acc[r].z += fmaxf((af[r].z + bf2f(bw0.z) + cc0 - st0.x) * st0.y * gv[r].z + bv[r].z, 0.f);
                acc[r].w += fmaxf((af[r].w + bf2f(bw0.w) + cc0 - st0.x) * st0.y * gv[r].w + bv[r].w, 0.f);
                acc[r].x += fmaxf((af[r].x + bf2f(bw1.x) + cc1 - st1.x) * st1.y * gv[r].x + bv[r].x, 0.f);
                acc[r].y += fmaxf((af[r].y + bf2f(bw1.y) + cc1 - st1.x) * st1.y * gv[r].y + bv[r].y, 0.f);
                acc[r].z += fmaxf((af[r].z + bf2f(bw1.z) + cc1 - st1.x) * st1.y * gv[r].z + bv[r].z, 0.f);
                acc[r].w += fmaxf((af[r].w + bf2f(bw1.w) + cc1 - st1.x) * st1.y * gv[r].w + bv[r].w, 0.f);
                acc[r].x += fmaxf((af[r].x + bf2f(bw2.x) + cc2 - st2.x) * st2.y * gv[r].x + bv[r].x, 0.f);
                acc[r].y += fmaxf((af[r].y + bf2f(bw2.y) + cc2 - st2.x) * st2.y * gv[r].y + bv[r].y, 0.f);
                acc[r].z += fmaxf((af[r].z + bf2f(bw2.z) + cc2 - st2.x) * st2.y * gv[r].z + bv[r].z, 0.f);
                acc[r].w += fmaxf((af[r].w + bf2f(bw2.w) + cc2 - st2.x) * st2.y * gv[r].w + bv[r].w, 0.f);
                acc[r].x += fmaxf((af[r].x + bf2f(bw3.x) + cc3 - st3.x) * st3.y * gv[r].x + bv[r].x, 0.f);
                acc[r].y += fmaxf((af[r].y + bf2f(bw3.y) + cc3 - st3.x) * st3.y * gv[r].y + bv[r].y, 0.f);
                acc[r].z += fmaxf((af[r].z + bf2f(bw3.z) + cc3 - st3.x) * st3.y * gv[r].z + bv[r].z, 0.f);
                acc[r].w += fmaxf((af[r].w + bf2f(bw3.w) + cc3 - st3.x) * st3.y * gv[r].w + bv[r].w, 0.f);
            }
        }
    }
    for (; k + 1 < hi; k += 2) {
        int e0 = elist[k], e1 = elist[k + 1];
        int s0 = srcArr[e0], s1 = srcArr[e1];
        float2 st0 = stats[e0], st1 = stats[e1];
        const ushort4* B0 = (const ushort4*)(Bbf + (size_t)s0 * CH + (size_t)cg8 * 1920);
        const ushort4* B1 = (const ushort4*)(Bbf + (size_t)s1 * CH + (size_t)cg8 * 1920);
        const float* c0 = cbuf + (size_t)e0 * 256 + cg8 * 32;
        const float* c1 = cbuf + (size_t)e1 * 256 + cg8 * 32;
#pragma unroll
        for (int r = 0; r < 2; ++r) {
            if (r == 0 || act1) {
                int i = tid + 256 * r;
                ushort4 bw0 = B0[i];
                ushort4 bw1 = B1[i];
                float cc0 = c0[ci[r]];
                float cc1 = c1[ci[r]];
                acc[r].x += fmaxf((af[r].x + bf2f(bw0.x) + cc0 - st0.x) * st0.y * gv[r].x + bv[r].x, 0.f);
                acc[r].y += fmaxf((af[r].y + bf2f(bw0.y) + cc0 - st0.x) * st0.y * gv[r].y + bv[r].y, 0.f);
                acc[r].z += fmaxf((af[r].z + bf2f(bw0.z) + cc0 - st0.x) * st0.y * gv[r].z + bv[r].z, 0.f);
                acc[r].w += fmaxf((af[r].w + bf2f(bw0.w) + cc0 - st0.x) * st0.y * gv[r].w + bv[r].w, 0.f);
                acc[r].x += fmaxf((af[r].x + bf2f(bw1.x) + cc1 - st1.x) * st1.y * gv[r].x + bv[r].x, 0.f);
                acc[r].y += fmaxf((af[r].y + bf2f(bw1.y) + cc1 - st1.x) * st1.y * gv[r].y + bv[r].y, 0.f);
                acc[r].z += fmaxf((af[r].z + bf2f(bw1.z) + cc1 - st1.x) * st1.y * gv[r].z + bv[r].z, 0.f);
                acc[r].w += fmaxf((af[r].w + bf2f(bw1.w) + cc1 - st1.x) * st1.y * gv[r].w + bv[r].w, 0.f);
            }
        }
    }
    if (k < hi) {
        int e = elist[k];
        int s = srcArr[e];
        float2 st = stats[e];
        const ushort4* Bb = (const ushort4*)(Bbf + (size_t)s * CH + (size_t)cg8 * 1920);
        const float* cc = cbuf + (size_t)e * 256 + cg8 * 32;
#pragma unroll
        for (int r = 0; r < 2; ++r) {
            if (r == 0 || act1) {
                int i = tid + 256 * r;
                float ccv = cc[ci[r]];
                ushort4 bw = Bb[i];
                acc[r].x += fmaxf((af[r].x + bf2f(bw.x) + ccv - st.x) * st.y * gv[r].x + bv[r].x, 0.f);
                acc[r].y += fmaxf((af[r].y + bf2f(bw.y) + ccv - st.x) * st.y * gv[r].y + bv[r].y, 0.f);
                acc[r].z += fmaxf((af[r].z + bf2f(bw.z) + ccv - st.x) * st.y * gv[r].z + bv[r].z, 0.f);
                acc[r].w += fmaxf((af[r].w + bf2f(bw.w) + ccv - st.x) * st.y * gv[r].w + bv[r].w, 0.f);
            }
        }
    }
    float4* ob = (float4*)(out + sbase);
#pragma unroll
    for (int r = 0; r < 2; ++r)
        if (r == 0 || act1) ob[tid + 256 * r] = acc[r];
}

extern "C" void kernel_launch(void* const* d_in, const int* in_sizes, int n_in,
                              void* d_out, int out_size, void* d_ws, size_t ws_size,
                              hipStream_t stream) {
    const float* x     = (const float*)d_in[0];
    const float* ea    = (const float*)d_in[1];
    const int*   ei    = (const int*)d_in[2];
    const float* We    = (const float*)d_in[3];
    const float* be    = (const float*)d_in[4];
    const float* Wc    = (const float*)d_in[5];
    const float* gamma = (const float*)d_in[6];
    const float* beta  = (const float*)d_in[7];
    const int E = in_sizes[2] / 2;
    const int* src = ei;
    const int* dst = ei + E;

    char* ws = (char*)d_ws;
    size_t off = 0;
    auto alloc = [&](size_t bytes) -> void* {
        void* p = ws + off;
        off += (bytes + 255) & ~(size_t)255;
        return p;
    };
    unsigned short* Abf    = (unsigned short*)alloc((size_t)N_NODES * CH * 2);
    unsigned short* Bbf    = (unsigned short*)alloc((size_t)N_NODES * CH * 2);
    float*          cbuf   = (float*)alloc((size_t)E * 256 * 4);
    float2*         stats  = (float2*)alloc((size_t)E * 8);
    unsigned short* Wfrag  = (unsigned short*)alloc(512 * 256 * 2);
    float*          M      = (float*)alloc(5 * 256 * 4);
    float*          bias0  = (float*)alloc(256 * 4);
    float*          RAB    = (float*)alloc((size_t)N_NODES * 512 * 4);
    float4*         Sc     = (float4*)alloc((size_t)N_NODES * 16);
    float*          Gp8    = (float*)alloc((size_t)E * 8 * 4);
    int*            offs   = (int*)alloc((N_NODES + 1) * 4);
    int*            elist  = (int*)alloc((size_t)E * 4);

    int ndot = ((E + 3) / 4) * 8;
    k_setup<<<128, 1024, 0, stream>>>(Wc, Wfrag);
    k_node_mfma<<<dim3(N_NODES, 2), 256, 0, stream>>>(x, Wfrag, Abf, Bbf);
    k_prepdots<<<2 + N_NODES + ndot, 256, 0, stream>>>(Abf, Bbf, Wc, We, be, src, dst, E,
                                                       RAB, Sc, M, bias0, offs, elist, Gp8);
    k_stats2<<<(E + 3) / 4, 256, 0, stream>>>(ea, M, bias0, src, dst, E, RAB, Sc, Gp8,
                                              cbuf, stats);
    k_apply<<<N_NODES * 8, 256, 0, stream>>>(Abf, Bbf, cbuf, stats, src, offs, elist,
                                             gamma, beta, (float*)d_out);
}

// Round 19
// 83.868 us; speedup vs baseline: 1.3366x; 1.0174x over previous
//
#include <hip/hip_runtime.h>

#define N_NODES 384
#define CCH 256        // channels
#define HT 60          // height
#define CH (CCH*HT)    // 15360 elements per node slab
#define CH4 (CH/4)     // 3840 4-vectors
#define LN_EPS 1e-5f

typedef __attribute__((ext_vector_type(8))) short bf16x8;
typedef __attribute__((ext_vector_type(4))) float f32x4;

__device__ inline unsigned short f2bf(float f) {
    unsigned int u = __float_as_uint(f);
    unsigned int r = (u + 0x7FFF + ((u >> 16) & 1)) >> 16;   // RNE
    return (unsigned short)r;
}
__device__ inline float bf2f(unsigned short u) {
    return __uint_as_float(((unsigned int)u) << 16);
}

// ---- setup: blocks 0..127 Wfrag; block 128 CSR; block 129 M/bias0.
// CSR & M depend only on inputs -> hoisted off the post-GEMM critical path.
__global__ __launch_bounds__(1024) void k_setup(const float* __restrict__ Wc,
                                                const float* __restrict__ We,
                                                const float* __restrict__ be,
                                                const int* __restrict__ dst, int E,
                                                unsigned short* __restrict__ Wfrag,
                                                float* __restrict__ M,
                                                float* __restrict__ bias0,
                                                int* __restrict__ offs,
                                                int* __restrict__ elist) {
    int tid = threadIdx.x;
    if (blockIdx.x < 128) {
        int idx = blockIdx.x * 1024 + tid;             // 131072 total
        int j = idx & 7, lane = (idx >> 3) & 63, ks = (idx >> 9) & 7, mt = idx >> 12;
        int o = mt * 16 + (lane & 15);
        int c = ks * 32 + (lane >> 4) * 8 + j;
        float v;
        if (o < 256) v = Wc[o * 768 + c] - Wc[o * 768 + 256 + c];   // W1 - W2
        else         v = Wc[(o - 256) * 768 + 256 + c];             // W2
        Wfrag[idx] = f2bf(v);
        return;
    }
    if (blockIdx.x == 129) {
        // ---- M/bias0 (threads 0..255) ----
        if (tid < 256) {
            int o = tid;
            float m0=0,m1=0,m2=0,m3=0,m4=0,bb=0;
            for (int k = 0; k < 256; ++k) {
                float w3 = Wc[o * 768 + 512 + k];
                m0 += We[0*256+k] * w3;
                m1 += We[1*256+k] * w3;
                m2 += We[2*256+k] * w3;
                m3 += We[3*256+k] * w3;
                m4 += We[4*256+k] * w3;
                bb += be[k] * w3;
            }
            M[0*256+o]=m0; M[1*256+o]=m1; M[2*256+o]=m2; M[3*256+o]=m3; M[4*256+o]=m4;
            bias0[o] = bb;
        }
        return;
    }
    // ---- block 128: CSR build (all 1024 threads), deterministic ----
    __shared__ int cnt[N_NODES];
    __shared__ int pos[512];
    for (int i = tid; i < N_NODES; i += 1024) cnt[i] = 0;
    __syncthreads();
    for (int e = tid; e < E; e += 1024) atomicAdd(&cnt[dst[e]], 1);
    __syncthreads();
    if (tid < 512) pos[tid] = (tid < N_NODES) ? cnt[tid] : 0;
    __syncthreads();
    for (int d = 1; d < 512; d <<= 1) {
        int t = 0;
        if (tid < 512 && tid >= d) t = pos[tid - d];
        __syncthreads();
        if (tid < 512) pos[tid] += t;
        __syncthreads();
    }
    if (tid < N_NODES) cnt[tid] = (tid == 0) ? 0 : pos[tid - 1];
    if (tid == 0) offs[0] = 0;
    if (tid < N_NODES) offs[tid + 1] = pos[tid];
    __syncthreads();
    for (int e = tid; e < E; e += 1024) {
        int d = dst[e];
        int slot = atomicAdd(&cnt[d], 1);
        elist[slot] = e;
    }
    __syncthreads();
    for (int n = tid; n < N_NODES; n += 1024) {
        int lo = (n == 0) ? 0 : pos[n - 1], hi = pos[n];
        for (int i = lo + 1; i < hi; ++i) {
            int key = elist[i]; int j = i - 1;
            while (j >= lo && elist[j] > key) { elist[j + 1] = elist[j]; --j; }
            elist[j + 1] = key;
        }
    }
}

// ---- per-node GEMM via MFMA, split by h-half: block (n, half) computes
// [A;B](512 x 32h) = Wstacked(512x256) @ x[n](256 x 32h). x read ONCE total.
__global__ __launch_bounds__(256) void k_node_mfma(const float* __restrict__ x,
                                                   const unsigned short* __restrict__ Wfrag,
                                                   unsigned short* __restrict__ Abf,
                                                   unsigned short* __restrict__ Bbf) {
    __shared__ unsigned short xT[32 * 256];   // 16 KiB, [h_local][c] bf16, swizzled
    int n = blockIdx.x, half = blockIdx.y, tid = threadIdx.x;

    const float4* xg = (const float4*)(x + (size_t)n * CH);
    if (half == 0) {
        for (int i = tid; i < 2048; i += 256) {
            int c = i >> 3, jj = i & 7;
            int r0 = jj * 4;
            float4 v = xg[c * 15 + jj];
            xT[(r0+0) * 256 + (c ^ (((r0+0) & 7) << 3))] = f2bf(v.x);
            xT[(r0+1) * 256 + (c ^ (((r0+1) & 7) << 3))] = f2bf(v.y);
            xT[(r0+2) * 256 + (c ^ (((r0+2) & 7) << 3))] = f2bf(v.z);
            xT[(r0+3) * 256 + (c ^ (((r0+3) & 7) << 3))] = f2bf(v.w);
        }
    } else {
        for (int i = tid; i < 4 * 256; i += 256) {
            int r = 28 + (i >> 8), c = i & 255;
            xT[r * 256 + (c ^ ((r & 7) << 3))] = 0;
        }
        for (int i = tid; i < 1792; i += 256) {
            int c = i / 7, jj = i - c * 7;
            int r0 = jj * 4;
            float4 v = xg[c * 15 + 8 + jj];
            xT[(r0+0) * 256 + (c ^ (((r0+0) & 7) << 3))] = f2bf(v.x);
            xT[(r0+1) * 256 + (c ^ (((r0+1) & 7) << 3))] = f2bf(v.y);
            xT[(r0+2) * 256 + (c ^ (((r0+2) & 7) << 3))] = f2bf(v.z);
            xT[(r0+3) * 256 + (c ^ (((r0+3) & 7) << 3))] = f2bf(v.w);
        }
    }
    __syncthreads();

    int w = tid >> 6, lane = tid & 63;
    int l15 = lane & 15, lg = lane >> 4;

    f32x4 acc[8][2];
#pragma unroll
    for (int mt = 0; mt < 8; ++mt)
#pragma unroll
        for (int nt = 0; nt < 2; ++nt)
            acc[mt][nt] = (f32x4){0.f, 0.f, 0.f, 0.f};

    const unsigned short* wbase = Wfrag + ((size_t)(w * 8) * 8) * 64 * 8;
    for (int ks = 0; ks < 8; ++ks) {
        bf16x8 bfr[2];
#pragma unroll
        for (int nt = 0; nt < 2; ++nt) {
            int row = nt * 16 + l15;
            int col = ks * 32 + lg * 8;
            int idx = row * 256 + (col ^ ((row & 7) << 3));
            bfr[nt] = *(const bf16x8*)(&xT[idx]);
        }
#pragma unroll
        for (int mt = 0; mt < 8; ++mt) {
            const bf16x8 afr = *(const bf16x8*)(wbase + (((size_t)mt * 8 + ks) * 64 + lane) * 8);
#pragma unroll
            for (int nt = 0; nt < 2; ++nt)
                acc[mt][nt] = __builtin_amdgcn_mfma_f32_16x16x32_bf16(afr, bfr[nt], acc[mt][nt], 0, 0, 0);
        }
    }

#pragma unroll
    for (int mt = 0; mt < 8; ++mt) {
        int mtg = w * 8 + mt;
        int obase = mtg * 16 + 4 * lg;
        unsigned short* dst0 = (obase < 256)
            ? (Abf + (size_t)n * CH + (size_t)obase * 60)
            : (Bbf + (size_t)n * CH + (size_t)(obase - 256) * 60);
#pragma unroll
        for (int nt = 0; nt < 2; ++nt) {
            int h = half * 32 + nt * 16 + l15;
            if (h < 60) {
#pragma unroll
                for (int r = 0; r < 4; ++r)
                    dst0[r * 60 + h] = f2bf(acc[mt][nt][r]);
            }
        }
    }
}

// ---- prep + dots: b0..383 per-node scalars; b384.. per-(edge,eighth) dots ----
__global__ __launch_bounds__(256) void k_prepdots(const unsigned short* __restrict__ Abf,
                                                  const unsigned short* __restrict__ Bbf,
                                                  const int* __restrict__ srcA,
                                                  const int* __restrict__ dstA, int E,
                                                  float* __restrict__ RAB,
                                                  float4* __restrict__ Sc,
                                                  float* __restrict__ Gp8) {
    int b = blockIdx.x;
    int tid = threadIdx.x, w = tid >> 6, lane = tid & 63;
    if (b < N_NODES) {
        // ---- per-node scalars: RA/RB row sums, SA/QA/SB/QB totals ----
        __shared__ float red[16];
        int n = b;
        const ushort4* Ab = (const ushort4*)(Abf + (size_t)n * CH + tid * 60);
        const ushort4* Bb = (const ushort4*)(Bbf + (size_t)n * CH + tid * 60);
        float rsA = 0.f, qA = 0.f, rsB = 0.f, qB = 0.f;
#pragma unroll
        for (int i = 0; i < 15; ++i) {
            ushort4 a = Ab[i], bb2 = Bb[i];
#pragma unroll
            for (int j = 0; j < 4; ++j) {
                float va = bf2f(((const unsigned short*)&a)[j]);
                float vb = bf2f(((const unsigned short*)&bb2)[j]);
                rsA += va; qA += va * va;
                rsB += vb; qB += vb * vb;
            }
        }
        RAB[(size_t)n * 512 + tid] = rsA;
        RAB[(size_t)n * 512 + 256 + tid] = rsB;
        float sA = rsA, sB = rsB;
#pragma unroll
        for (int o = 32; o >= 1; o >>= 1) {
            sA += __shfl_xor(sA, o, 64); qA += __shfl_xor(qA, o, 64);
            sB += __shfl_xor(sB, o, 64); qB += __shfl_xor(qB, o, 64);
        }
        if (lane == 0) { red[w*4]=sA; red[w*4+1]=qA; red[w*4+2]=sB; red[w*4+3]=qB; }
        __syncthreads();
        if (tid == 0) {
            Sc[n] = make_float4(red[0]+red[4]+red[8]+red[12],
                                red[1]+red[5]+red[9]+red[13],
                                red[2]+red[6]+red[10]+red[14],
                                red[3]+red[7]+red[11]+red[15]);
        }
        return;
    }
    // ---- cross-dots: wave per (edge, eighth). cg8 = g&7 keeps stride-8 blocks
    // on one XCD -> that XCD's A/B eighths (2x1.48 MB) stay L2-resident.
    {
        int g = b - N_NODES;
        int cg8 = g & 7;
        int ew = g >> 3;
        int e = ew * 4 + w;
        if (e >= E) return;
        int s = srcA[e], d = dstA[e];
        const ushort4* Ab = (const ushort4*)(Abf + (size_t)d * CH + (size_t)cg8 * 1920);
        const ushort4* Bb = (const ushort4*)(Bbf + (size_t)s * CH + (size_t)cg8 * 1920);
        float dot = 0.f;
#pragma unroll
        for (int r = 0; r < 7; ++r) {            // 480 = 7*64 + 32 ushort4
            int i = lane + 64 * r;
            ushort4 a = Ab[i], bb2 = Bb[i];
            dot += bf2f(a.x) * bf2f(bb2.x) + bf2f(a.y) * bf2f(bb2.y)
                 + bf2f(a.z) * bf2f(bb2.z) + bf2f(a.w) * bf2f(bb2.w);
        }
        if (lane < 32) {
            int i = lane + 448;
            ushort4 a = Ab[i], bb2 = Bb[i];
            dot += bf2f(a.x) * bf2f(bb2.x) + bf2f(a.y) * bf2f(bb2.y)
                 + bf2f(a.z) * bf2f(bb2.z) + bf2f(a.w) * bf2f(bb2.w);
        }
#pragma unroll
        for (int o2 = 32; o2 >= 1; o2 >>= 1)
            dot += __shfl_xor(dot, o2, 64);
        if (lane == 0) Gp8[(size_t)e * 8 + cg8] = dot;
    }
}

// ---- per-edge stats (edge-coefficient + LN stats assembly; Gp8 gather) ----
__global__ __launch_bounds__(256) void k_stats2(const float* __restrict__ ea,
                                                const float* __restrict__ M,
                                                const float* __restrict__ bias0,
                                                const int* __restrict__ srcA,
                                                const int* __restrict__ dstA, int E,
                                                const float* __restrict__ RAB,
                                                const float4* __restrict__ Sc,
                                                const float* __restrict__ Gp8,
                                                float* __restrict__ cbuf,
                                                float2* __restrict__ stats) {
    int w = threadIdx.x >> 6, lane = threadIdx.x & 63;
    int e = blockIdx.x * 4 + w;
    if (e >= E) return;
    int s = srcA[e], d = dstA[e];
    float ev0 = ea[e*5], ev1 = ea[e*5+1], ev2 = ea[e*5+2], ev3 = ea[e*5+3], ev4 = ea[e*5+4];
    float sc = 0.f, sc2 = 0.f, dots = 0.f;
#pragma unroll
    for (int r = 0; r < 4; ++r) {
        int o = lane + 64 * r;
        float c = bias0[o] + ev0*M[o] + ev1*M[256+o] + ev2*M[512+o] + ev3*M[768+o] + ev4*M[1024+o];
        cbuf[(size_t)e * 256 + o] = c;
        sc += c; sc2 += c * c;
        dots += (RAB[(size_t)d * 512 + o] + RAB[(size_t)s * 512 + 256 + o]) * c;
    }
    float g = (lane < 8) ? Gp8[(size_t)e * 8 + lane] : 0.f;
#pragma unroll
    for (int o2 = 32; o2 >= 1; o2 >>= 1) {
        sc   += __shfl_xor(sc, o2, 64);
        sc2  += __shfl_xor(sc2, o2, 64);
        dots += __shfl_xor(dots, o2, 64);
        g    += __shfl_xor(g, o2, 64);
    }
    if (lane == 0) {
        float4 scd = Sc[d], scs = Sc[s];
        float S1 = scd.x + scs.z + 60.f * sc;
        float S2 = scd.y + scs.w + 60.f * sc2 + 2.f * (g + dots);
        float mu = S1 * (1.0f / (float)CH);
        float var = S2 * (1.0f / (float)CH) - mu * mu;
        stats[e] = make_float2(mu, rsqrtf(var + LN_EPS));
    }
}

// ---- apply + aggregate: 8-way channel split, XCD affinity, edge unroll x2 ----
__global__ __launch_bounds__(256) void k_apply(const unsigned short* __restrict__ Abf,
                                               const unsigned short* __restrict__ Bbf,
                                               const float* __restrict__ cbuf,
                                               const float2* __restrict__ stats,
                                               const int* __restrict__ srcArr,
                                               const int* __restrict__ offsets,
                                               const int* __restrict__ elist,
                                               const float* __restrict__ gamma,
                                               const float* __restrict__ beta,
                                               float* __restrict__ out) {
    int b = blockIdx.x;
    int cg8 = b & 7;
    int n = b >> 3;
    int tid = threadIdx.x;
    size_t sbase = (size_t)n * CH + (size_t)cg8 * 1920;
    const ushort4* Ab = (const ushort4*)(Abf + sbase);
    const float4*  g4 = (const float4*)(gamma + (size_t)cg8 * 1920);
    const float4*  b4 = (const float4*)(beta  + (size_t)cg8 * 1920);
    bool act1 = (tid < 224);                   // 480 = 256 + 224 vec4s

    float4 af[2], gv[2], bv[2], acc[2];
    int ci[2];
#pragma unroll
    for (int r = 0; r < 2; ++r) {
        acc[r] = make_float4(0.f, 0.f, 0.f, 0.f);
        af[r] = make_float4(0.f, 0.f, 0.f, 0.f);
        gv[r] = make_float4(0.f, 0.f, 0.f, 0.f);
        bv[r] = make_float4(0.f, 0.f, 0.f, 0.f);
        ci[r] = 0;
    }
#pragma unroll
    for (int r = 0; r < 2; ++r) {
        if (r == 0 || act1) {
            int i = tid + 256 * r;
            ci[r] = i / 15;                    // channel within eighth (0..31)
            ushort4 aw = Ab[i];
            af[r].x = bf2f(aw.x); af[r].y = bf2f(aw.y);
            af[r].z = bf2f(aw.z); af[r].w = bf2f(aw.w);
            gv[r] = g4[i];
            bv[r] = b4[i];
        }
    }

    int lo = offsets[n], hi = offsets[n + 1];
    int k = lo;
    for (; k + 1 < hi; k += 2) {
        int e0 = elist[k], e1 = elist[k + 1];
        int s0 = srcArr[e0], s1 = srcArr[e1];
        float2 st0 = stats[e0], st1 = stats[e1];
        const ushort4* B0 = (const ushort4*)(Bbf + (size_t)s0 * CH + (size_t)cg8 * 1920);
        const ushort4* B1 = (const ushort4*)(Bbf + (size_t)s1 * CH + (size_t)cg8 * 1920);
        const float* c0 = cbuf + (size_t)e0 * 256 + cg8 * 32;
        const float* c1 = cbuf + (size_t)e1 * 256 + cg8 * 32;
#pragma unroll
        for (int r = 0; r < 2; ++r) {
            if (r == 0 || act1) {
                int i = tid + 256 * r;
                ushort4 bw0 = B0[i];
                ushort4 bw1 = B1[i];
                float cc0 = c0[ci[r]];
                float cc1 = c1[ci[r]];
                acc[r].x += fmaxf((af[r].x + bf2f(bw0.x) + cc0 - st0.x) * st0.y * gv[r].x + bv[r].x, 0.f);
                acc[r].y += fmaxf((af[r].y + bf2f(bw0.y) + cc0 - st0.x) * st0.y * gv[r].y + bv[r].y, 0.f);
                acc[r].z += fmaxf((af[r].z + bf2f(bw0.z) + cc0 - st0.x) * st0.y * gv[r].z + bv[r].z, 0.f);
                acc[r].w += fmaxf((af[r].w + bf2f(bw0.w) + cc0 - st0.x) * st0.y * gv[r].w + bv[r].w, 0.f);
                acc[r].x += fmaxf((af[r].x + bf2f(bw1.x) + cc1 - st1.x) * st1.y * gv[r].x + bv[r].x, 0.f);
                acc[r].y += fmaxf((af[r].y + bf2f(bw1.y) + cc1 - st1.x) * st1.y * gv[r].y + bv[r].y, 0.f);
                acc[r].z += fmaxf((af[r].z + bf2f(bw1.z) + cc1 - st1.x) * st1.y * gv[r].z + bv[r].z, 0.f);
                acc[r].w += fmaxf((af[r].w + bf2f(bw1.w) + cc1 - st1.x) * st1.y * gv[r].w + bv[r].w, 0.f);
            }
        }
    }
    if (k < hi) {
        int e = elist[k];
        int s = srcArr[e];
        float2 st = stats[e];
        const ushort4* Bb = (const ushort4*)(Bbf + (size_t)s * CH + (size_t)cg8 * 1920);
        const float* cc = cbuf + (size_t)e * 256 + cg8 * 32;
#pragma unroll
        for (int r = 0; r < 2; ++r) {
            if (r == 0 || act1) {
                int i = tid + 256 * r;
                float ccv = cc[ci[r]];
                ushort4 bw = Bb[i];
                acc[r].x += fmaxf((af[r].x + bf2f(bw.x) + ccv - st.x) * st.y * gv[r].x + bv[r].x, 0.f);
                acc[r].y += fmaxf((af[r].y + bf2f(bw.y) + ccv - st.x) * st.y * gv[r].y + bv[r].y, 0.f);
                acc[r].z += fmaxf((af[r].z + bf2f(bw.z) + ccv - st.x) * st.y * gv[r].z + bv[r].z, 0.f);
                acc[r].w += fmaxf((af[r].w + bf2f(bw.w) + ccv - st.x) * st.y * gv[r].w + bv[r].w, 0.f);
            }
        }
    }
    float4* ob = (float4*)(out + sbase);
#pragma unroll
    for (int r = 0; r < 2; ++r)
        if (r == 0 || act1) ob[tid + 256 * r] = acc[r];
}

extern "C" void kernel_launch(void* const* d_in, const int* in_sizes, int n_in,
                              void* d_out, int out_size, void* d_ws, size_t ws_size,
                              hipStream_t stream) {
    const float* x     = (const float*)d_in[0];
    const float* ea    = (const float*)d_in[1];
    const int*   ei    = (const int*)d_in[2];
    const float* We    = (const float*)d_in[3];
    const float* be    = (const float*)d_in[4];
    const float* Wc    = (const float*)d_in[5];
    const float* gamma = (const float*)d_in[6];
    const float* beta  = (const float*)d_in[7];
    const int E = in_sizes[2] / 2;
    const int* src = ei;
    const int* dst = ei + E;

    char* ws = (char*)d_ws;
    size_t off = 0;
    auto alloc = [&](size_t bytes) -> void* {
        void* p = ws + off;
        off += (bytes + 255) & ~(size_t)255;
        return p;
    };
    unsigned short* Abf    = (unsigned short*)alloc((size_t)N_NODES * CH * 2);
    unsigned short* Bbf    = (unsigned short*)alloc((size_t)N_NODES * CH * 2);
    float*          cbuf   = (float*)alloc((size_t)E * 256 * 4);
    float2*         stats  = (float2*)alloc((size_t)E * 8);
    unsigned short* Wfrag  = (unsigned short*)alloc(512 * 256 * 2);
    float*          M      = (float*)alloc(5 * 256 * 4);
    float*          bias0  = (float*)alloc(256 * 4);
    float*          RAB    = (float*)alloc((size_t)N_NODES * 512 * 4);
    float4*         Sc     = (float4*)alloc((size_t)N_NODES * 16);
    float*          Gp8    = (float*)alloc((size_t)E * 8 * 4);
    int*            offs   = (int*)alloc((N_NODES + 1) * 4);
    int*            elist  = (int*)alloc((size_t)E * 4);

    int ndot = ((E + 3) / 4) * 8;
    k_setup<<<130, 1024, 0, stream>>>(Wc, We, be, dst, E, Wfrag, M, bias0, offs, elist);
    k_node_mfma<<<dim3(N_NODES, 2), 256, 0, stream>>>(x, Wfrag, Abf, Bbf);
    k_prepdots<<<N_NODES + ndot, 256, 0, stream>>>(Abf, Bbf, src, dst, E, RAB, Sc, Gp8);
    k_stats2<<<(E + 3) / 4, 256, 0, stream>>>(ea, M, bias0, src, dst, E, RAB, Sc, Gp8,
                                              cbuf, stats);
    k_apply<<<N_NODES * 8, 256, 0, stream>>>(Abf, Bbf, cbuf, stats, src, offs, elist,
                                             gamma, beta, (float*)d_out);
}